// Round 7
// baseline (4405.182 us; speedup 1.0000x reference)
//
#include <hip/hip_runtime.h>
#include <stdint.h>

#define AGENT __HIP_MEMORY_SCOPE_AGENT
typedef unsigned long long u64;

// x[64][256][256] -> xT[t][k][b]  (k-major, batch-minor: consumers read
// x[k][b..b+3] as float4). Reads are per-lane rows (uncoalesced, one-shot
// 16MB kernel); writes coalesce per k (256B/instr).
__global__ __launch_bounds__(256) void xpose_in(const float* __restrict__ x,
                                                float* __restrict__ xT) {
  const int t = blockIdx.x;
  const int b = threadIdx.x & 63;
  const int w = threadIdx.x >> 6;
  const float* xr = x + ((size_t)b * 256 + t) * 256;
  float* o = xT + (size_t)t * 256 * 64;
  for (int kq = w * 16; kq < w * 16 + 16; ++kq) {
    float4 v = *(const float4*)(xr + kq * 4);
    o[(size_t)(kq * 4 + 0) * 64 + b] = v.x;
    o[(size_t)(kq * 4 + 1) * 64 + b] = v.y;
    o[(size_t)(kq * 4 + 2) * 64 + b] = v.z;
    o[(size_t)(kq * 4 + 3) * 64 + b] = v.w;
  }
}

// Pack [W;U] ([KT][4H]) into quad-major per-WG blocks:
//   out[((wg*KTq + q)*16 + c)*4 + j] = WU[k=4q+j][col = g*H + wg*4 + jl],
// c = g*4 + jl. One b128 = one c-row x 4 k's. Worker stages the whole WG
// block (48KB max) into LDS once; reads are 4-unique-address b128
// (lane cq in {0..3}) -> 2-way bank conflict = free (m136).
__global__ __launch_bounds__(256) void pack_wu(const float* __restrict__ W,
                                               const float* __restrict__ U,
                                               float* __restrict__ out,
                                               int DIN, int H) {
  __shared__ float tile[64][65];
  const int KT = DIN + H;
  const int KTq = KT >> 2;
  const int c0 = blockIdx.x * 64;  // column tile base (4H dim)
  const int k0 = blockIdx.y * 64;  // k tile base
  const int tx = threadIdx.x & 63;
  const int ty = threadIdx.x >> 6;
  for (int r = ty; r < 64; r += 4) {
    const int k = k0 + r;
    tile[r][tx] = (k < DIN) ? W[(size_t)k * (4 * H) + c0 + tx]
                            : U[(size_t)(k - DIN) * (4 * H) + c0 + tx];
  }
  __syncthreads();
  // tile[a][b] = WU[k0+a][c0+b]; thread (r,tx) emits (col=c0+r, k=k0+tx)
  for (int r = ty; r < 64; r += 4) {
    const int cg = c0 + r;
    const int g = cg / H;
    const int col = cg - g * H;
    const int wg = col >> 2;
    const int jl = col & 3;
    const int c = (g << 2) | jl;
    const int k = k0 + tx;
    const int q = k >> 2;
    const int j = k & 3;
    out[(((size_t)wg * KTq + q) * 16 + c) * 4 + j] = tile[tx][r];
  }
}

#define SB __builtin_amdgcn_sched_barrier(0)
// Round-1 lesson: macro params must NOT be named x/y/z/w (member capture).
// x0_..x3_ are the quad's 4 k-vectors (component M_ = batch j), W_ is one
// c-row's 4 k-weights (components = k).
#define FMA_K4(A_, W_, M_)                                            \
  A_ = fmaf((W_).x, x0_.M_, A_); A_ = fmaf((W_).y, x1_.M_, A_);       \
  A_ = fmaf((W_).z, x2_.M_, A_); A_ = fmaf((W_).w, x3_.M_, A_);
#define FMA_ROW16(W_, O_)      \
  FMA_K4(acc[(O_) + 0], W_, x) \
  FMA_K4(acc[(O_) + 1], W_, y) \
  FMA_K4(acc[(O_) + 2], W_, z) \
  FMA_K4(acc[(O_) + 3], W_, w)

// Register-tile accumulate — EXACT round-4 structure (3826us best; rounds
// 5/6 proved source-level pipelining regresses: +VALU addr math, +VGPR,
// compiler already schedules within the group). Per quad: 4 ds_read_b128
// (w rows, 4-unique-addr broadcast) + 4 global dwordx4 (x[k][4b],
// L2-served) + 64 fma; groups of 4 quads (2 for QW=2) between
// sched_barriers. Latency hiding now comes from OCCUPANCY (round-7: 8
// waves/WG, ~4 waves/SIMD) instead of in-wave lookahead.
// lane = (cq = lane>>4, bq = lane&15); acc[i][j] = z(c=cq*4+i, b=bq*4+j).
template <int QW>
__device__ __forceinline__ void accum_cb(const float4* __restrict__ src4,
                                         const float4* __restrict__ wl4,
                                         int bq, int cq4, float acc[16]) {
  constexpr int G = (QW % 4 == 0) ? 4 : 2;
  static_assert(QW % G == 0, "");
#pragma unroll 1
  for (int g = 0; g < QW; g += G) {
#pragma unroll
    for (int ql = g; ql < g + G; ++ql) {
      const float4 x0_ = src4[(size_t)ql * 64 + 0 * 16 + bq];
      const float4 x1_ = src4[(size_t)ql * 64 + 1 * 16 + bq];
      const float4 x2_ = src4[(size_t)ql * 64 + 2 * 16 + bq];
      const float4 x3_ = src4[(size_t)ql * 64 + 3 * 16 + bq];
      const float4 w0_ = wl4[ql * 16 + cq4 + 0];
      const float4 w1_ = wl4[ql * 16 + cq4 + 1];
      const float4 w2_ = wl4[ql * 16 + cq4 + 2];
      const float4 w3_ = wl4[ql * 16 + cq4 + 3];
      FMA_ROW16(w0_, 0)
      FMA_ROW16(w1_, 4)
      FMA_ROW16(w2_, 8)
      FMA_ROW16(w3_, 12)
    }
    SB;  // cap live regs per group (VGPR must stay <=128 for 4 waves/SIMD)
  }
}

// Dedicated per-layer aggregator: one wave gathers this layer's NWG per-WG
// flags for tick t, then publishes a single monotonic epoch word (= ticks
// completed). Consumers poll ONLY the epoch word (1 lane, 1 line).
template <int NWG>
__device__ __forceinline__ void agg_body(unsigned* __restrict__ flg,
                                         unsigned* __restrict__ ep) {
  const int tid = threadIdx.x;
  if (tid >= 64) return;  // single wave
  for (int t = 0; t < 256; ++t) {
    unsigned* base = flg + (size_t)t * NWG;
    if (NWG <= 64) {
      if (tid < NWG) {
        while (__hip_atomic_load(base + tid, __ATOMIC_RELAXED, AGENT) == 0u)
          __builtin_amdgcn_s_sleep(1);
      }
    } else {
      while (__hip_atomic_load(base + tid, __ATOMIC_RELAXED, AGENT) == 0u)
        __builtin_amdgcn_s_sleep(1);
      while (__hip_atomic_load(base + 64 + tid, __ATOMIC_RELAXED, AGENT) == 0u)
        __builtin_amdgcn_s_sleep(1);
    }
    asm volatile("s_waitcnt vmcnt(0)" ::: "memory");
    if (tid == 0)
      __hip_atomic_store(ep, (unsigned)(t + 1), __ATOMIC_RELAXED, AGENT);
  }
}

// One pipelined LSTM layer, 512-thread WG (round-7: 8 waves, K-split 8 —
// doubles waves/SIMD to ~4 so memory stalls interleave; total FMA issue
// per CU unchanged; round-4's 35% VALUBusy was 2-wave TLP starvation).
// WG owns hidden quad wg (4 units); all 16 weight rows staged ONCE into
// LDS. lane = (cq,bq) register tile. Reduction: waves 0-3 write sZ[wv]
// (phase A), waves 4-7 merge into sZ[wv-4] (phase B, deterministic),
// epilogue (waves 0-3, wave jl owns unit jl) sums 4 merged slices.
// h stored [t][unit][b]. Sync: per-WG flags -> aggregator -> epoch word.
template <int DIN, int H, int NWG, bool FIN, bool XCOH>
__device__ __forceinline__ void layer_body(
    int wg, int tid, const float* __restrict__ xin, float* __restrict__ hseq,
    const float* __restrict__ wP, const float* __restrict__ bias,
    float* __restrict__ dout, unsigned* __restrict__ selfF,
    unsigned* __restrict__ selfE, unsigned* __restrict__ prevE,
    float* __restrict__ wL, float (*sZ)[16][64], float* sH) {
  constexpr int KT = DIN + H;
  constexpr int KTq = KT / 4;
  constexpr int QX = DIN / 32;  // x-quads per wave (K-split 8)
  constexpr int QH = H / 32;    // h-quads per wave
  constexpr int T = 256;
  static_assert(QX == 2 || QX % 4 == 0, "");
  static_assert(QH == 2 || QH % 4 == 0, "");

  const int lane = tid & 63;
  const int wv = tid >> 6;          // 0..7: K-split slice
  const int jw = wv & 3;            // epilogue unit (waves 0-3 only)
  const int bq = lane & 15;         // batch quad (4 batches)
  const int cq4 = (lane >> 4) * 4;  // first of this lane's 4 c-rows

  // ---- stage the WG's full weight block into LDS (once), layout [q][c] ----
  {
    float4* wl = (float4*)wL;
    const float4* wp = (const float4*)wP + (size_t)wg * KTq * 16;
    for (int i = tid; i < KTq * 16; i += 512) wl[i] = wp[i];
  }
  const float4* wl4x = (const float4*)wL + (size_t)wv * QX * 16;
  const float4* wl4h = (const float4*)wL + ((size_t)(DIN / 4) + wv * QH) * 16;

  float bz[4];
#pragma unroll
  for (int g = 0; g < 4; ++g) bz[g] = bias[g * H + wg * 4 + jw];
  float cst = 0.f;
  __syncthreads();

  for (int t = 0; t < T; ++t) {
    float acc[16];
#pragma unroll
    for (int c = 0; c < 16; ++c) acc[c] = 0.f;

    if (!XCOH) {
      // layer 0: x static — overlap input projection with waiting for peers
      accum_cb<QX>((const float4*)(xin + (size_t)t * DIN * 64) +
                       (size_t)wv * QX * 64,
                   wl4x, bq, cq4, acc);
    }
    // single-lane epoch polls: tid 0 -> own layer (t-1 done); tid 64 -> prev
    if (t > 0 && tid == 0) {
      while (__hip_atomic_load(selfE, __ATOMIC_RELAXED, AGENT) < (unsigned)t)
        __builtin_amdgcn_s_sleep(2);
    }
    if (XCOH && tid == 64) {
      while (__hip_atomic_load(prevE, __ATOMIC_RELAXED, AGENT) <
             (unsigned)(t + 1))
        __builtin_amdgcn_s_sleep(2);
    }
    __syncthreads();
    asm volatile("" ::: "memory");  // no compiler hoist of loads above polls

    if (XCOH) {
      accum_cb<QX>((const float4*)(xin + (size_t)t * DIN * 64) +
                       (size_t)wv * QX * 64,
                   wl4x, bq, cq4, acc);
    }
    if (t > 0) {
      accum_cb<QH>((const float4*)(hseq + (size_t)(t - 1) * H * 64) +
                       (size_t)wv * QH * 64,
                   wl4h, bq, cq4, acc);
    }

    // ---- 8-way K-split reduction, two deterministic phases ----
    // phase A: waves 0-3 write their slice
    if (wv < 4) {
#pragma unroll
      for (int i = 0; i < 4; ++i) {
        *(float4*)&sZ[wv][cq4 + i][bq * 4] = make_float4(
            acc[i * 4 + 0], acc[i * 4 + 1], acc[i * 4 + 2], acc[i * 4 + 3]);
      }
    }
    __syncthreads();
    // phase B: waves 4-7 merge into partner slice (disjoint RMW)
    if (wv >= 4) {
#pragma unroll
      for (int i = 0; i < 4; ++i) {
        float4 v = *(const float4*)&sZ[wv - 4][cq4 + i][bq * 4];
        v.x += acc[i * 4 + 0];
        v.y += acc[i * 4 + 1];
        v.z += acc[i * 4 + 2];
        v.w += acc[i * 4 + 3];
        *(float4*)&sZ[wv - 4][cq4 + i][bq * 4] = v;
      }
    }
    __syncthreads();

    // epilogue: waves 0-3, wave jw owns unit jw
    if (wv < 4) {
      float z[4];
#pragma unroll
      for (int g = 0; g < 4; ++g) {
        z[g] = bz[g];
#pragma unroll
        for (int k = 0; k < 4; ++k) z[g] += sZ[k][g * 4 + jw][lane];
      }
      const float ig = 1.f / (1.f + __expf(-z[0]));
      const float fg = 1.f / (1.f + __expf(-z[1]));
      const float gg = FIN ? tanhf(z[2]) : fmaxf(z[2], 0.f);
      const float og = 1.f / (1.f + __expf(-z[3]));
      cst = fg * cst + ig * gg;
      const float ca = FIN ? tanhf(cst) : fmaxf(cst, 0.f);
      const float h = og * ca;
      sH[lane * 4 + jw] = h;  // [b][jl]
      if (FIN && t == T - 1) dout[(size_t)lane * H + wg * 4 + jw] = h;
    }
    __syncthreads();

    // wave 0 publishes the WG's 4 unit-rows in [t][unit][b] layout
    // (agent write-through, coalesced 256B per row), then signals.
    if (wv == 0) {
      float* hw = hseq + (size_t)t * H * 64 + (size_t)(wg * 4) * 64 + lane;
#pragma unroll
      for (int jl = 0; jl < 4; ++jl) {
        __hip_atomic_store(hw + jl * 64, sH[lane * 4 + jl], __ATOMIC_RELAXED,
                           AGENT);
      }
      asm volatile("s_waitcnt vmcnt(0)" ::: "memory");
      if (tid == 0)
        __hip_atomic_store(&selfF[t * NWG + wg], 1u, __ATOMIC_RELAXED, AGENT);
    }
  }
}

__global__ __launch_bounds__(512, 4) void lstm_fused(
    const float* __restrict__ xT, float* __restrict__ h0,
    float* __restrict__ h1, float* __restrict__ h2, float* __restrict__ h3,
    float* __restrict__ h4, float* __restrict__ h5,
    const float* __restrict__ wuT0, const float* __restrict__ wuT1,
    const float* __restrict__ wuT2, const float* __restrict__ wuT3,
    const float* __restrict__ wuT4, const float* __restrict__ wuT5,
    const float* __restrict__ b0, const float* __restrict__ b1,
    const float* __restrict__ b2, const float* __restrict__ b3,
    const float* __restrict__ b4, const float* __restrict__ b5,
    float* __restrict__ dout, unsigned* __restrict__ f0,
    unsigned* __restrict__ f1, unsigned* __restrict__ f2,
    unsigned* __restrict__ f3, unsigned* __restrict__ f4,
    unsigned* __restrict__ f5, unsigned* __restrict__ eps) {
  __shared__ alignas(16) float wLDS[16 * 768];  // 48 KB (max KTq=192)
  __shared__ alignas(16) float sZ[4][16][64];   // 16 KB
  __shared__ alignas(16) float sH[256];         // 1 KB
  // 65KB/WG -> 2 blocks/CU; 470 blocks <= 512 capacity (co-residency safe).
  // launch_bounds(512,4): 4 waves/EU min -> VGPR capped at 128 so two
  // 8-wave blocks fit per CU (round-4 accum measured 104; headroom ok).
  const int b = blockIdx.x;
  const int tid = threadIdx.x;
  // heavy layers (L0, L4) first so they land one-per-CU; aggregators last
  if (b < 128) {
    layer_body<256, 512, 128, false, false>(b, tid, xT, h0, wuT0, b0, nullptr,
                                            f0, eps + 0, nullptr, wLDS, sZ, sH);
  } else if (b < 256) {
    layer_body<256, 512, 128, false, true>(b - 128, tid, h3, h4, wuT4, b4,
                                           nullptr, f4, eps + 4, eps + 3, wLDS,
                                           sZ, sH);
  } else if (b < 320) {
    layer_body<512, 256, 64, false, true>(b - 256, tid, h0, h1, wuT1, b1,
                                          nullptr, f1, eps + 1, eps + 0, wLDS,
                                          sZ, sH);
  } else if (b < 384) {
    layer_body<64, 256, 64, false, true>(b - 320, tid, h2, h3, wuT3, b3,
                                         nullptr, f3, eps + 3, eps + 2, wLDS,
                                         sZ, sH);
  } else if (b < 448) {
    layer_body<512, 256, 64, true, true>(b - 384, tid, h4, h5, wuT5, b5, dout,
                                         f5, eps + 5, eps + 4, wLDS, sZ, sH);
  } else if (b < 464) {
    layer_body<256, 64, 16, false, true>(b - 448, tid, h1, h2, wuT2, b2,
                                         nullptr, f2, eps + 2, eps + 1, wLDS,
                                         sZ, sH);
  } else {
    const int l = b - 464;
    if (l == 0) agg_body<128>(f0, eps + 0);
    else if (l == 1) agg_body<64>(f1, eps + 1);
    else if (l == 2) agg_body<16>(f2, eps + 2);
    else if (l == 3) agg_body<64>(f3, eps + 3);
    else if (l == 4) agg_body<128>(f4, eps + 4);
    else agg_body<64>(f5, eps + 5);
  }
}

extern "C" void kernel_launch(void* const* d_in, const int* in_sizes, int n_in,
                              void* d_out, int out_size, void* d_ws,
                              size_t ws_size, hipStream_t stream) {
  (void)in_sizes; (void)n_in; (void)out_size; (void)ws_size;
  const float* x = (const float*)d_in[0];
  const float* W[6];
  const float* U[6];
  const float* B[6];
  for (int l = 0; l < 6; ++l) {
    W[l] = (const float*)d_in[1 + 3 * l];
    U[l] = (const float*)d_in[2 + 3 * l];
    B[l] = (const float*)d_in[3 + 3 * l];
  }
  char* ws = (char*)d_ws;
  // flags: [T][NWG] per layer; NWG = 128,64,16,64,128,64; then 6 epochs
  unsigned* f0 = (unsigned*)ws;
  unsigned* f1 = f0 + 128 * 256;
  unsigned* f2 = f1 + 64 * 256;
  unsigned* f3 = f2 + 16 * 256;
  unsigned* f4 = f3 + 64 * 256;
  unsigned* f5 = f4 + 128 * 256;
  unsigned* eps = f0 + 464 * 256;
  float* wuT0 = (float*)(ws + (1u << 20));
  float* wuT1 = wuT0 + (size_t)2048 * 768;
  float* wuT2 = wuT1 + (size_t)1024 * 768;
  float* wuT3 = wuT2 + (size_t)256 * 320;
  float* wuT4 = wuT3 + (size_t)1024 * 320;
  float* wuT5 = wuT4 + (size_t)2048 * 768;
  float* xT = (float*)(ws + (22u << 20));   // 16 MB
  float* h0 = (float*)(ws + (38u << 20));   // 32 MB
  float* h1 = (float*)(ws + (70u << 20));   // 16 MB
  float* h2 = (float*)(ws + (86u << 20));   // 4 MB
  float* h3 = (float*)(ws + (90u << 20));   // 16 MB
  float* h4 = (float*)(ws + (106u << 20));  // 32 MB
  float* h5 = (float*)(ws + (138u << 20));  // 16 MB (full T, no ring)

  hipMemsetAsync(f0, 0, (464 * 256 + 8) * sizeof(unsigned), stream);
  xpose_in<<<256, 256, 0, stream>>>(x, xT);
  pack_wu<<<dim3(32, 12), 256, 0, stream>>>(W[0], U[0], wuT0, 256, 512);
  pack_wu<<<dim3(16, 12), 256, 0, stream>>>(W[1], U[1], wuT1, 512, 256);
  pack_wu<<<dim3(4, 5), 256, 0, stream>>>(W[2], U[2], wuT2, 256, 64);
  pack_wu<<<dim3(16, 5), 256, 0, stream>>>(W[3], U[3], wuT3, 64, 256);
  pack_wu<<<dim3(32, 12), 256, 0, stream>>>(W[4], U[4], wuT4, 256, 512);
  pack_wu<<<dim3(16, 12), 256, 0, stream>>>(W[5], U[5], wuT5, 512, 256);

  lstm_fused<<<470, 512, 0, stream>>>(xT, h0, h1, h2, h3, h4, h5, wuT0, wuT1,
                                      wuT2, wuT3, wuT4, wuT5, B[0], B[1], B[2],
                                      B[3], B[4], B[5], (float*)d_out, f0, f1,
                                      f2, f3, f4, f5, eps);
}

// Round 8
// 4078.782 us; speedup vs baseline: 1.0800x; 1.0800x over previous
//
#include <hip/hip_runtime.h>
#include <stdint.h>

#define AGENT __HIP_MEMORY_SCOPE_AGENT
typedef unsigned long long u64;

// x[64][256][256] -> xT[t][k][b]  (k-major, batch-minor; contiguous [k][b]
// panels are DMA'd to LDS 1KB/instr by consumers).
__global__ __launch_bounds__(256) void xpose_in(const float* __restrict__ x,
                                                float* __restrict__ xT) {
  const int t = blockIdx.x;
  const int b = threadIdx.x & 63;
  const int w = threadIdx.x >> 6;
  const float* xr = x + ((size_t)b * 256 + t) * 256;
  float* o = xT + (size_t)t * 256 * 64;
  for (int kq = w * 16; kq < w * 16 + 16; ++kq) {
    float4 v = *(const float4*)(xr + kq * 4);
    o[(size_t)(kq * 4 + 0) * 64 + b] = v.x;
    o[(size_t)(kq * 4 + 1) * 64 + b] = v.y;
    o[(size_t)(kq * 4 + 2) * 64 + b] = v.z;
    o[(size_t)(kq * 4 + 3) * 64 + b] = v.w;
  }
}

// Pack [W;U] ([KT][4H]) into quad-major per-WG blocks:
//   out[((wg*KTq + q)*16 + c)*4 + j] = WU[k=4q+j][col = g*H + wg*4 + jl],
// c = g*4 + jl. One b128 = one c-row x 4 k's; 4-distinct-address broadcast
// reads (2-way bank alias = free, m136).
__global__ __launch_bounds__(256) void pack_wu(const float* __restrict__ W,
                                               const float* __restrict__ U,
                                               float* __restrict__ out,
                                               int DIN, int H) {
  __shared__ float tile[64][65];
  const int KT = DIN + H;
  const int KTq = KT >> 2;
  const int c0 = blockIdx.x * 64;  // column tile base (4H dim)
  const int k0 = blockIdx.y * 64;  // k tile base
  const int tx = threadIdx.x & 63;
  const int ty = threadIdx.x >> 6;
  for (int r = ty; r < 64; r += 4) {
    const int k = k0 + r;
    tile[r][tx] = (k < DIN) ? W[(size_t)k * (4 * H) + c0 + tx]
                            : U[(size_t)(k - DIN) * (4 * H) + c0 + tx];
  }
  __syncthreads();
  for (int r = ty; r < 64; r += 4) {
    const int cg = c0 + r;
    const int g = cg / H;
    const int col = cg - g * H;
    const int wg = col >> 2;
    const int jl = col & 3;
    const int c = (g << 2) | jl;
    const int k = k0 + tx;
    const int q = k >> 2;
    const int j = k & 3;
    out[(((size_t)wg * KTq + q) * 16 + c) * 4 + j] = tile[tx][r];
  }
}

#define SB __builtin_amdgcn_sched_barrier(0)
// Round-1 lesson: macro params must NOT be named x/y/z/w (member capture).
#define FMA_K4(A_, W_, M_)                                            \
  A_ = fmaf((W_).x, x0_.M_, A_); A_ = fmaf((W_).y, x1_.M_, A_);       \
  A_ = fmaf((W_).z, x2_.M_, A_); A_ = fmaf((W_).w, x3_.M_, A_);
#define FMA_ROW16(W_, O_)      \
  FMA_K4(acc[(O_) + 0], W_, x) \
  FMA_K4(acc[(O_) + 1], W_, y) \
  FMA_K4(acc[(O_) + 2], W_, z) \
  FMA_K4(acc[(O_) + 3], W_, w)

// Async global->LDS DMA, width 16B/lane: lane i's 16B lands at ldsbase+i*16
// (linear — matches our [k][b] panel layout exactly).
typedef const __attribute__((address_space(1))) void* gas_t;
typedef __attribute__((address_space(3))) void* las_t;
#define GLDS(G_, L_) \
  __builtin_amdgcn_global_load_lds((gas_t)(const void*)(G_), \
                                   (las_t)(void*)(L_), 16, 0, 0)
// Stage one 2-quad chunk C_ (2KB, 2 coalesced 1KB instrs) into buffer P_.
#define STAGE2(C_, P_)                                            \
  {                                                               \
    const float4* g_ = src4 + (size_t)(C_)*128 + lane;            \
    float* l_ = xb + (P_)*512;                                    \
    GLDS(g_, l_);                                                 \
    GLDS(g_ + 64, l_ + 256);                                      \
  }

// Round-8: consumer x/h path moved off the L1 return bus (round-7 showed a
// per-CU pipe saturated: occupancy 2x -> VALUBusy DOWN; the 16-distinct-addr
// dwordx4 x-loads deliver 1024B/instr through L1 at ~64B/cyc = ~10us/CU/tick
// = the whole stall). Now: global_load_lds DMA (1KB unique, coalesced) into
// per-wave triple-buffered 2-quad LDS chunks; counted vmcnt(4) distance-2
// pipeline (T3/T4 recipe: asm waitcnt + sched_barrier, never vmcnt(0)
// mid-loop); x read back as b128 broadcast (4-lane shared = LDS crossbar
// broadcast, 2-way bank alias free). w-path and FMA order unchanged.
// lane = (cq = lane>>4, bq = lane&15); acc[i][j] = z(c=cq*4+i, b=bq*4+j).
template <int QW>
__device__ __forceinline__ void accum_lds(const float4* __restrict__ src4,
                                          float* __restrict__ xb,
                                          const float4* __restrict__ wl4,
                                          int lane, int bq, int cq4,
                                          float acc[16]) {
  static_assert(QW % 2 == 0 && QW >= 4, "");
  constexpr int NC = QW / 2;  // 2-quad chunks
  STAGE2(0, 0)
  STAGE2(1, 1)
  int pc = 0, pn = 2;  // c%3, (c+2)%3
#pragma unroll 1
  for (int c = 0; c < NC; ++c) {
    if (c + 2 < NC) {
      STAGE2(c + 2, pn)
      asm volatile("s_waitcnt vmcnt(4)" ::: "memory");  // chunk c resident
    } else {
      asm volatile("s_waitcnt vmcnt(0)" ::: "memory");  // tail drain
    }
    SB;
    const float4* wq_ = wl4 + (size_t)c * 32;
    const float* xc_ = xb + pc * 512;
#pragma unroll
    for (int q = 0; q < 2; ++q) {
      const float4* xq_ = (const float4*)(xc_ + q * 256);
      const float4 x0_ = xq_[0 + bq];
      const float4 x1_ = xq_[16 + bq];
      const float4 x2_ = xq_[32 + bq];
      const float4 x3_ = xq_[48 + bq];
      const float4 w0_ = wq_[q * 16 + cq4 + 0];
      const float4 w1_ = wq_[q * 16 + cq4 + 1];
      const float4 w2_ = wq_[q * 16 + cq4 + 2];
      const float4 w3_ = wq_[q * 16 + cq4 + 3];
      FMA_ROW16(w0_, 0)
      FMA_ROW16(w1_, 4)
      FMA_ROW16(w2_, 8)
      FMA_ROW16(w3_, 12)
    }
    SB;
    pc = (pc == 2) ? 0 : pc + 1;
    pn = (pn == 2) ? 0 : pn + 1;
  }
}

// Dedicated per-layer aggregator: one wave gathers this layer's NWG per-WG
// flags for tick t, then publishes a single monotonic epoch word.
template <int NWG>
__device__ __forceinline__ void agg_body(unsigned* __restrict__ flg,
                                         unsigned* __restrict__ ep) {
  const int tid = threadIdx.x;
  if (tid >= 64) return;  // single wave
  for (int t = 0; t < 256; ++t) {
    unsigned* base = flg + (size_t)t * NWG;
    if (NWG <= 64) {
      if (tid < NWG) {
        while (__hip_atomic_load(base + tid, __ATOMIC_RELAXED, AGENT) == 0u)
          __builtin_amdgcn_s_sleep(1);
      }
    } else {
      while (__hip_atomic_load(base + tid, __ATOMIC_RELAXED, AGENT) == 0u)
        __builtin_amdgcn_s_sleep(1);
      while (__hip_atomic_load(base + 64 + tid, __ATOMIC_RELAXED, AGENT) == 0u)
        __builtin_amdgcn_s_sleep(1);
    }
    asm volatile("s_waitcnt vmcnt(0)" ::: "memory");
    if (tid == 0)
      __hip_atomic_store(ep, (unsigned)(t + 1), __ATOMIC_RELAXED, AGENT);
  }
}

// One pipelined LSTM layer (round-4 structure + DMA'd x/h). 256-thread WG
// owns hidden quad wg; 16 weight rows in LDS (48KB max); K-split 4.
// LDS xU region (24KB) = per-wave xbuf[3][2KB] UNION sZ (16KB): sZ only
// live between the pre-reduction barrier (NEW — guards the alias: a wave
// writing sZ[wv] could clobber another wave's in-flight xbuf) and the
// epilogue; staging for the next tick starts after the sH barrier, when
// sZ is dead. sH is OUTSIDE the union (publish reads it concurrently with
// other waves' next-tick staging).
template <int DIN, int H, int NWG, bool FIN, bool XCOH>
__device__ __forceinline__ void layer_body(
    int wg, int tid, const float* __restrict__ xin, float* __restrict__ hseq,
    const float* __restrict__ wP, const float* __restrict__ bias,
    float* __restrict__ dout, unsigned* __restrict__ selfF,
    unsigned* __restrict__ selfE, unsigned* __restrict__ prevE,
    float* __restrict__ wL, float* __restrict__ xU, float* sH) {
  constexpr int KT = DIN + H;
  constexpr int KTq = KT / 4;
  constexpr int QX = DIN / 16;  // x-quads per wave (K-split 4)
  constexpr int QH = H / 16;    // h-quads per wave
  constexpr int T = 256;
  static_assert(QX % 2 == 0 && QH % 2 == 0, "");

  const int lane = tid & 63;
  const int wv = tid >> 6;          // K-split slice; also unit jl in epilogue
  const int bq = lane & 15;         // batch quad (4 batches)
  const int cq4 = (lane >> 4) * 4;  // first of this lane's 4 c-rows
  float (*sZ)[16][64] = (float(*)[16][64])xU;  // alias (see header comment)
  float* xb = xU + (size_t)wv * 1536;          // this wave's 3x2KB buffers

  // ---- stage the WG's full weight block into LDS (once), layout [q][c] ----
  {
    float4* wl = (float4*)wL;
    const float4* wp = (const float4*)wP + (size_t)wg * KTq * 16;
    for (int i = tid; i < KTq * 16; i += 256) wl[i] = wp[i];
  }
  const float4* wl4x = (const float4*)wL + (size_t)wv * QX * 16;
  const float4* wl4h = (const float4*)wL + ((size_t)(DIN / 4) + wv * QH) * 16;

  float bz[4];
#pragma unroll
  for (int g = 0; g < 4; ++g) bz[g] = bias[g * H + wg * 4 + wv];
  float cst = 0.f;
  __syncthreads();

  for (int t = 0; t < T; ++t) {
    float acc[16];
#pragma unroll
    for (int c = 0; c < 16; ++c) acc[c] = 0.f;

    if (!XCOH) {
      // layer 0: x static — overlap input projection with waiting for peers
      accum_lds<QX>((const float4*)(xin + (size_t)t * DIN * 64) +
                        (size_t)wv * QX * 64,
                    xb, wl4x, lane, bq, cq4, acc);
    }
    // single-lane epoch polls: tid 0 -> own layer (t-1 done); tid 64 -> prev
    if (t > 0 && tid == 0) {
      while (__hip_atomic_load(selfE, __ATOMIC_RELAXED, AGENT) < (unsigned)t)
        __builtin_amdgcn_s_sleep(2);
    }
    if (XCOH && tid == 64) {
      while (__hip_atomic_load(prevE, __ATOMIC_RELAXED, AGENT) <
             (unsigned)(t + 1))
        __builtin_amdgcn_s_sleep(2);
    }
    __syncthreads();
    asm volatile("" ::: "memory");  // no compiler hoist of loads above polls

    if (XCOH) {
      accum_lds<QX>((const float4*)(xin + (size_t)t * DIN * 64) +
                        (size_t)wv * QX * 64,
                    xb, wl4x, lane, bq, cq4, acc);
    }
    if (t > 0) {
      accum_lds<QH>((const float4*)(hseq + (size_t)(t - 1) * H * 64) +
                        (size_t)wv * QH * 64,
                    xb, wl4h, lane, bq, cq4, acc);
    }

    // all waves' accums (and their xbuf reads) done before sZ alias-write
    __syncthreads();
    // 4-way K-split reduction: thread (kb=wv, cq, bq) -> sZ[kb][c][b]
#pragma unroll
    for (int i = 0; i < 4; ++i) {
      *(float4*)&sZ[wv][cq4 + i][bq * 4] = make_float4(
          acc[i * 4 + 0], acc[i * 4 + 1], acc[i * 4 + 2], acc[i * 4 + 3]);
    }
    __syncthreads();

    float z[4];
#pragma unroll
    for (int g = 0; g < 4; ++g) {
      z[g] = bz[g];
#pragma unroll
      for (int k = 0; k < 4; ++k) z[g] += sZ[k][g * 4 + wv][lane];
    }
    const float ig = 1.f / (1.f + __expf(-z[0]));
    const float fg = 1.f / (1.f + __expf(-z[1]));
    const float gg = FIN ? tanhf(z[2]) : fmaxf(z[2], 0.f);
    const float og = 1.f / (1.f + __expf(-z[3]));
    cst = fg * cst + ig * gg;
    const float ca = FIN ? tanhf(cst) : fmaxf(cst, 0.f);
    const float h = og * ca;
    sH[lane * 4 + wv] = h;  // [b][jl]
    if (FIN && t == T - 1) dout[(size_t)lane * H + wg * 4 + wv] = h;
    __syncthreads();

    // wave 0 publishes the WG's 4 unit-rows in [t][unit][b] layout
    // (agent write-through, coalesced 256B per row), then signals.
    if (wv == 0) {
      float* hw = hseq + (size_t)t * H * 64 + (size_t)(wg * 4) * 64 + lane;
#pragma unroll
      for (int jl = 0; jl < 4; ++jl) {
        __hip_atomic_store(hw + jl * 64, sH[lane * 4 + jl], __ATOMIC_RELAXED,
                           AGENT);
      }
      asm volatile("s_waitcnt vmcnt(0)" ::: "memory");
      if (tid == 0)
        __hip_atomic_store(&selfF[t * NWG + wg], 1u, __ATOMIC_RELAXED, AGENT);
    }
  }
}

__global__ __launch_bounds__(256, 2) void lstm_fused(
    const float* __restrict__ xT, float* __restrict__ h0,
    float* __restrict__ h1, float* __restrict__ h2, float* __restrict__ h3,
    float* __restrict__ h4, float* __restrict__ h5,
    const float* __restrict__ wuT0, const float* __restrict__ wuT1,
    const float* __restrict__ wuT2, const float* __restrict__ wuT3,
    const float* __restrict__ wuT4, const float* __restrict__ wuT5,
    const float* __restrict__ b0, const float* __restrict__ b1,
    const float* __restrict__ b2, const float* __restrict__ b3,
    const float* __restrict__ b4, const float* __restrict__ b5,
    float* __restrict__ dout, unsigned* __restrict__ f0,
    unsigned* __restrict__ f1, unsigned* __restrict__ f2,
    unsigned* __restrict__ f3, unsigned* __restrict__ f4,
    unsigned* __restrict__ f5, unsigned* __restrict__ eps) {
  __shared__ alignas(16) float wLDS[16 * 768];  // 48 KB (max KTq=192)
  __shared__ alignas(16) float xU[4 * 3 * 512]; // 24 KB: xbuf U sZ
  __shared__ alignas(16) float sH[256];         // 1 KB (outside the union)
  // 73 KB/WG -> 2 blocks/CU (146KB of 160KB), co-residency safe.
  const int b = blockIdx.x;
  const int tid = threadIdx.x;
  // heavy layers (L0, L4) first so they land one-per-CU; aggregators last
  if (b < 128) {
    layer_body<256, 512, 128, false, false>(b, tid, xT, h0, wuT0, b0, nullptr,
                                            f0, eps + 0, nullptr, wLDS, xU, sH);
  } else if (b < 256) {
    layer_body<256, 512, 128, false, true>(b - 128, tid, h3, h4, wuT4, b4,
                                           nullptr, f4, eps + 4, eps + 3, wLDS,
                                           xU, sH);
  } else if (b < 320) {
    layer_body<512, 256, 64, false, true>(b - 256, tid, h0, h1, wuT1, b1,
                                          nullptr, f1, eps + 1, eps + 0, wLDS,
                                          xU, sH);
  } else if (b < 384) {
    layer_body<64, 256, 64, false, true>(b - 320, tid, h2, h3, wuT3, b3,
                                         nullptr, f3, eps + 3, eps + 2, wLDS,
                                         xU, sH);
  } else if (b < 448) {
    layer_body<512, 256, 64, true, true>(b - 384, tid, h4, h5, wuT5, b5, dout,
                                         f5, eps + 5, eps + 4, wLDS, xU, sH);
  } else if (b < 464) {
    layer_body<256, 64, 16, false, true>(b - 448, tid, h1, h2, wuT2, b2,
                                         nullptr, f2, eps + 2, eps + 1, wLDS,
                                         xU, sH);
  } else {
    const int l = b - 464;
    if (l == 0) agg_body<128>(f0, eps + 0);
    else if (l == 1) agg_body<64>(f1, eps + 1);
    else if (l == 2) agg_body<16>(f2, eps + 2);
    else if (l == 3) agg_body<64>(f3, eps + 3);
    else if (l == 4) agg_body<128>(f4, eps + 4);
    else agg_body<64>(f5, eps + 5);
  }
}

extern "C" void kernel_launch(void* const* d_in, const int* in_sizes, int n_in,
                              void* d_out, int out_size, void* d_ws,
                              size_t ws_size, hipStream_t stream) {
  (void)in_sizes; (void)n_in; (void)out_size; (void)ws_size;
  const float* x = (const float*)d_in[0];
  const float* W[6];
  const float* U[6];
  const float* B[6];
  for (int l = 0; l < 6; ++l) {
    W[l] = (const float*)d_in[1 + 3 * l];
    U[l] = (const float*)d_in[2 + 3 * l];
    B[l] = (const float*)d_in[3 + 3 * l];
  }
  char* ws = (char*)d_ws;
  // flags: [T][NWG] per layer; NWG = 128,64,16,64,128,64; then 6 epochs
  unsigned* f0 = (unsigned*)ws;
  unsigned* f1 = f0 + 128 * 256;
  unsigned* f2 = f1 + 64 * 256;
  unsigned* f3 = f2 + 16 * 256;
  unsigned* f4 = f3 + 64 * 256;
  unsigned* f5 = f4 + 128 * 256;
  unsigned* eps = f0 + 464 * 256;
  float* wuT0 = (float*)(ws + (1u << 20));
  float* wuT1 = wuT0 + (size_t)2048 * 768;
  float* wuT2 = wuT1 + (size_t)1024 * 768;
  float* wuT3 = wuT2 + (size_t)256 * 320;
  float* wuT4 = wuT3 + (size_t)1024 * 320;
  float* wuT5 = wuT4 + (size_t)2048 * 768;
  float* xT = (float*)(ws + (22u << 20));   // 16 MB
  float* h0 = (float*)(ws + (38u << 20));   // 32 MB
  float* h1 = (float*)(ws + (70u << 20));   // 16 MB
  float* h2 = (float*)(ws + (86u << 20));   // 4 MB
  float* h3 = (float*)(ws + (90u << 20));   // 16 MB
  float* h4 = (float*)(ws + (106u << 20));  // 32 MB
  float* h5 = (float*)(ws + (138u << 20));  // 16 MB (full T, no ring)

  hipMemsetAsync(f0, 0, (464 * 256 + 8) * sizeof(unsigned), stream);
  xpose_in<<<256, 256, 0, stream>>>(x, xT);
  pack_wu<<<dim3(32, 12), 256, 0, stream>>>(W[0], U[0], wuT0, 256, 512);
  pack_wu<<<dim3(16, 12), 256, 0, stream>>>(W[1], U[1], wuT1, 512, 256);
  pack_wu<<<dim3(4, 5), 256, 0, stream>>>(W[2], U[2], wuT2, 256, 64);
  pack_wu<<<dim3(16, 5), 256, 0, stream>>>(W[3], U[3], wuT3, 64, 256);
  pack_wu<<<dim3(32, 12), 256, 0, stream>>>(W[4], U[4], wuT4, 256, 512);
  pack_wu<<<dim3(16, 12), 256, 0, stream>>>(W[5], U[5], wuT5, 512, 256);

  lstm_fused<<<470, 256, 0, stream>>>(xT, h0, h1, h2, h3, h4, h5, wuT0, wuT1,
                                      wuT2, wuT3, wuT4, wuT5, B[0], B[1], B[2],
                                      B[3], B[4], B[5], (float*)d_out, f0, f1,
                                      f2, f3, f4, f5, eps);
}

// Round 9
// 3459.670 us; speedup vs baseline: 1.2733x; 1.1790x over previous
//
#include <hip/hip_runtime.h>
#include <stdint.h>

#define AGENT __HIP_MEMORY_SCOPE_AGENT
typedef unsigned long long u64;

// x[64][256][256] -> xT[t][k][b]  (k-major, batch-minor)
__global__ __launch_bounds__(256) void xpose_in(const float* __restrict__ x,
                                                float* __restrict__ xT) {
  const int t = blockIdx.x;
  const int b = threadIdx.x & 63;
  const int w = threadIdx.x >> 6;
  const float* xr = x + ((size_t)b * 256 + t) * 256;
  float* o = xT + (size_t)t * 256 * 64;
  for (int kq = w * 16; kq < w * 16 + 16; ++kq) {
    float4 v = *(const float4*)(xr + kq * 4);
    o[(size_t)(kq * 4 + 0) * 64 + b] = v.x;
    o[(size_t)(kq * 4 + 1) * 64 + b] = v.y;
    o[(size_t)(kq * 4 + 2) * 64 + b] = v.z;
    o[(size_t)(kq * 4 + 3) * 64 + b] = v.w;
  }
}

// Pack [W;U] ([KT][4H]) into quad-major per-WG blocks:
//   out[((wg*KTq + q)*16 + c)*4 + j] = WU[k=4q+j][col = g*H + wg*4 + jl],
// c = g*4 + jl. One b128 = one c-row x 4 k's.
__global__ __launch_bounds__(256) void pack_wu(const float* __restrict__ W,
                                               const float* __restrict__ U,
                                               float* __restrict__ out,
                                               int DIN, int H) {
  __shared__ float tile[64][65];
  const int KT = DIN + H;
  const int KTq = KT >> 2;
  const int c0 = blockIdx.x * 64;
  const int k0 = blockIdx.y * 64;
  const int tx = threadIdx.x & 63;
  const int ty = threadIdx.x >> 6;
  for (int r = ty; r < 64; r += 4) {
    const int k = k0 + r;
    tile[r][tx] = (k < DIN) ? W[(size_t)k * (4 * H) + c0 + tx]
                            : U[(size_t)(k - DIN) * (4 * H) + c0 + tx];
  }
  __syncthreads();
  for (int r = ty; r < 64; r += 4) {
    const int cg = c0 + r;
    const int g = cg / H;
    const int col = cg - g * H;
    const int wg = col >> 2;
    const int jl = col & 3;
    const int c = (g << 2) | jl;
    const int k = k0 + tx;
    const int q = k >> 2;
    const int j = k & 3;
    out[(((size_t)wg * KTq + q) * 16 + c) * 4 + j] = tile[tx][r];
  }
}

#define SB __builtin_amdgcn_sched_barrier(0)
// Round-1 lesson: macro params must NOT be named x/y/z/w (member capture).
// 8 fmas: one w-scalar WS_ times 8 batch values (two float4 halves).
#define FMA_B8(I_, WS_, XA_, XB_)                                   \
  acc[(I_) * 8 + 0] = fmaf(WS_, (XA_).x, acc[(I_) * 8 + 0]);        \
  acc[(I_) * 8 + 1] = fmaf(WS_, (XA_).y, acc[(I_) * 8 + 1]);        \
  acc[(I_) * 8 + 2] = fmaf(WS_, (XA_).z, acc[(I_) * 8 + 2]);        \
  acc[(I_) * 8 + 3] = fmaf(WS_, (XA_).w, acc[(I_) * 8 + 3]);        \
  acc[(I_) * 8 + 4] = fmaf(WS_, (XB_).x, acc[(I_) * 8 + 4]);        \
  acc[(I_) * 8 + 5] = fmaf(WS_, (XB_).y, acc[(I_) * 8 + 5]);        \
  acc[(I_) * 8 + 6] = fmaf(WS_, (XB_).z, acc[(I_) * 8 + 6]);        \
  acc[(I_) * 8 + 7] = fmaf(WS_, (XB_).w, acc[(I_) * 8 + 7]);
// One c-row over the quad's 4 k's (WV_ components = k).
#define FMA_ROW32(I_, WV_)                 \
  FMA_B8(I_, (WV_).x, x0a_, x0b_)          \
  FMA_B8(I_, (WV_).y, x1a_, x1b_)          \
  FMA_B8(I_, (WV_).z, x2a_, x2b_)          \
  FMA_B8(I_, (WV_).w, x3a_, x3b_)

// Round-9: (8c,8b) register tile. Rounds 4/7/8 all ticked ~16.6us because
// the binder is OPERAND-FILL INSTRUCTIONS: tile (4c,4b) = 8 FMA/fill ->
// 3072 fill-instrs/CU/tick x ~13cyc = 40k cyc = the whole tick. Ratio =
// 4NbNc/(Nb+Nc): (8,8) = 16 FMA/fill -> 1536 fills, split 768 VMEM (x) ||
// 768 LDS (w), both under the 5.1us FMA floor.
// Wave lanes = (cq = lane>>5 in {0,1}, k4 = (lane>>3)&3, bq = lane&7):
// 16 (cq,bq) tiles x 4 intra-wave K-slices. acc[i*8+j] = partial
// z(c = cq*8+i, b = bq*8+j) for K-slice (wv*4+k4).
// Per quad: 8 x-loads (dwordx4, base+imm<=784) + 8 w ds_read_b128
// (2-distinct-addr broadcast) + 256 FMA. sp pre-offset by bq*2, wp by cq*8.
template <int QL>
__device__ __forceinline__ void accum88(const float4* __restrict__ sp,
                                        const float4* __restrict__ wp,
                                        float acc[64]) {
#pragma unroll 1
  for (int q = 0; q < QL; ++q) {
    const float4 x0a_ = sp[0],  x0b_ = sp[1];
    const float4 x1a_ = sp[16], x1b_ = sp[17];
    const float4 x2a_ = sp[32], x2b_ = sp[33];
    const float4 x3a_ = sp[48], x3b_ = sp[49];
    const float4 w0_ = wp[0], w1_ = wp[1], w2_ = wp[2], w3_ = wp[3];
    const float4 w4_ = wp[4], w5_ = wp[5], w6_ = wp[6], w7_ = wp[7];
    FMA_ROW32(0, w0_)
    FMA_ROW32(1, w1_)
    FMA_ROW32(2, w2_)
    FMA_ROW32(3, w3_)
    FMA_ROW32(4, w4_)
    FMA_ROW32(5, w5_)
    FMA_ROW32(6, w6_)
    FMA_ROW32(7, w7_)
    SB;  // cap live regs per quad (64 acc + 64 buf must not balloon)
    sp += 64;
    wp += 16;
  }
}

// Dedicated per-layer aggregator: one wave gathers this layer's NWG per-WG
// flags for tick t, then publishes a single monotonic epoch word.
template <int NWG>
__device__ __forceinline__ void agg_body(unsigned* __restrict__ flg,
                                         unsigned* __restrict__ ep) {
  const int tid = threadIdx.x;
  if (tid >= 64) return;  // single wave
  for (int t = 0; t < 256; ++t) {
    unsigned* base = flg + (size_t)t * NWG;
    if (NWG <= 64) {
      if (tid < NWG) {
        while (__hip_atomic_load(base + tid, __ATOMIC_RELAXED, AGENT) == 0u)
          __builtin_amdgcn_s_sleep(1);
      }
    } else {
      while (__hip_atomic_load(base + tid, __ATOMIC_RELAXED, AGENT) == 0u)
        __builtin_amdgcn_s_sleep(1);
      while (__hip_atomic_load(base + 64 + tid, __ATOMIC_RELAXED, AGENT) == 0u)
        __builtin_amdgcn_s_sleep(1);
    }
    asm volatile("s_waitcnt vmcnt(0)" ::: "memory");
    if (tid == 0)
      __hip_atomic_store(ep, (unsigned)(t + 1), __ATOMIC_RELAXED, AGENT);
  }
}

// One pipelined LSTM layer. 256-thread WG owns hidden quad wg (4 units);
// 16 weight rows staged ONCE into LDS (48KB max, quad-major). 16 K-slices
// (4 waves x 4 intra-wave via lane k4). After accum: 2-round ds_swizzle
// butterfly over lane bits 3-4 (xor8=0x201F, xor16=0x401F) merges the 4
// intra-wave slices -> wave partials -> EXISTING sZ[4] reduction, epilogue
// (wave jl owns unit jl), publish, and flag/epoch sync all unchanged.
template <int DIN, int H, int NWG, bool FIN, bool XCOH>
__device__ __forceinline__ void layer_body(
    int wg, int tid, const float* __restrict__ xin, float* __restrict__ hseq,
    const float* __restrict__ wP, const float* __restrict__ bias,
    float* __restrict__ dout, unsigned* __restrict__ selfF,
    unsigned* __restrict__ selfE, unsigned* __restrict__ prevE,
    float* __restrict__ wL, float (*sZ)[16][64], float* sH) {
  constexpr int KT = DIN + H;
  constexpr int KTq = KT / 4;
  constexpr int QLX = DIN / 64;  // quads per lane-slice (x part)
  constexpr int QLH = H / 64;    // quads per lane-slice (h part)
  constexpr int T = 256;
  static_assert(DIN % 64 == 0 && H % 64 == 0, "16-way K-slicing");

  const int lane = tid & 63;
  const int wv = tid >> 6;           // wave: K-quarter; unit jl in epilogue
  const int cq = lane >> 5;          // c-half (8 rows)
  const int k4 = (lane >> 3) & 3;    // intra-wave K-slice (lane bits 3-4)
  const int bq = lane & 7;           // batch octet
  const int slice = wv * 4 + k4;     // global K-slice 0..15

  // ---- stage the WG's full weight block into LDS (once), layout [q][c] ----
  {
    float4* wl = (float4*)wL;
    const float4* wp = (const float4*)wP + (size_t)wg * KTq * 16;
    for (int i = tid; i < KTq * 16; i += 256) wl[i] = wp[i];
  }
  const float4* wl4 = (const float4*)wL;

  float bz[4];
#pragma unroll
  for (int g = 0; g < 4; ++g) bz[g] = bias[g * H + wg * 4 + wv];
  float cst = 0.f;
  __syncthreads();

  for (int t = 0; t < T; ++t) {
    float acc[64];
#pragma unroll
    for (int c = 0; c < 64; ++c) acc[c] = 0.f;

    if (!XCOH) {
      // layer 0: x static — overlap input projection with waiting for peers
      accum88<QLX>((const float4*)(xin + (size_t)t * DIN * 64) +
                       (size_t)slice * QLX * 64 + bq * 2,
                   wl4 + (size_t)slice * QLX * 16 + cq * 8, acc);
    }
    // single-lane epoch polls: tid 0 -> own layer (t-1 done); tid 64 -> prev
    if (t > 0 && tid == 0) {
      while (__hip_atomic_load(selfE, __ATOMIC_RELAXED, AGENT) < (unsigned)t)
        __builtin_amdgcn_s_sleep(2);
    }
    if (XCOH && tid == 64) {
      while (__hip_atomic_load(prevE, __ATOMIC_RELAXED, AGENT) <
             (unsigned)(t + 1))
        __builtin_amdgcn_s_sleep(2);
    }
    __syncthreads();
    asm volatile("" ::: "memory");  // no compiler hoist of loads above polls

    if (XCOH) {
      accum88<QLX>((const float4*)(xin + (size_t)t * DIN * 64) +
                       (size_t)slice * QLX * 64 + bq * 2,
                   wl4 + (size_t)slice * QLX * 16 + cq * 8, acc);
    }
    if (t > 0) {
      accum88<QLH>((const float4*)(hseq + (size_t)(t - 1) * H * 64) +
                       (size_t)slice * QLH * 64 + bq * 2,
                   wl4 + (size_t)(DIN / 4 + slice * QLH) * 16 + cq * 8, acc);
    }

    // ---- intra-wave K-merge: butterfly over lane bits 3-4 (all lanes) ----
#pragma unroll
    for (int r = 0; r < 64; ++r) {
      const int v = __builtin_amdgcn_ds_swizzle(__float_as_int(acc[r]),
                                                0x201F);  // xor lane^8
      acc[r] += __int_as_float(v);
    }
#pragma unroll
    for (int r = 0; r < 64; ++r) {
      const int v = __builtin_amdgcn_ds_swizzle(__float_as_int(acc[r]),
                                                0x401F);  // xor lane^16
      acc[r] += __int_as_float(v);
    }

    // wave partial -> sZ[wv][c][b] (k4==0 lanes carry the merged values)
    if (k4 == 0) {
#pragma unroll
      for (int i = 0; i < 8; ++i) {
#pragma unroll
        for (int h = 0; h < 2; ++h) {
          *(float4*)&sZ[wv][cq * 8 + i][bq * 8 + h * 4] =
              make_float4(acc[i * 8 + h * 4 + 0], acc[i * 8 + h * 4 + 1],
                          acc[i * 8 + h * 4 + 2], acc[i * 8 + h * 4 + 3]);
        }
      }
    }
    __syncthreads();

    float z[4];
#pragma unroll
    for (int g = 0; g < 4; ++g) {
      z[g] = bz[g];
#pragma unroll
      for (int k = 0; k < 4; ++k) z[g] += sZ[k][g * 4 + wv][lane];
    }
    const float ig = 1.f / (1.f + __expf(-z[0]));
    const float fg = 1.f / (1.f + __expf(-z[1]));
    const float gg = FIN ? tanhf(z[2]) : fmaxf(z[2], 0.f);
    const float og = 1.f / (1.f + __expf(-z[3]));
    cst = fg * cst + ig * gg;
    const float ca = FIN ? tanhf(cst) : fmaxf(cst, 0.f);
    const float h = og * ca;
    sH[lane * 4 + wv] = h;  // [b][jl]
    if (FIN && t == T - 1) dout[(size_t)lane * H + wg * 4 + wv] = h;
    __syncthreads();

    // wave 0 publishes the WG's 4 unit-rows in [t][unit][b] layout
    // (agent write-through, coalesced 256B per row), then signals.
    if (wv == 0) {
      float* hw = hseq + (size_t)t * H * 64 + (size_t)(wg * 4) * 64 + lane;
#pragma unroll
      for (int jl = 0; jl < 4; ++jl) {
        __hip_atomic_store(hw + jl * 64, sH[lane * 4 + jl], __ATOMIC_RELAXED,
                           AGENT);
      }
      asm volatile("s_waitcnt vmcnt(0)" ::: "memory");
      if (tid == 0)
        __hip_atomic_store(&selfF[t * NWG + wg], 1u, __ATOMIC_RELAXED, AGENT);
    }
  }
}

__global__ __launch_bounds__(256, 2) void lstm_fused(
    const float* __restrict__ xT, float* __restrict__ h0,
    float* __restrict__ h1, float* __restrict__ h2, float* __restrict__ h3,
    float* __restrict__ h4, float* __restrict__ h5,
    const float* __restrict__ wuT0, const float* __restrict__ wuT1,
    const float* __restrict__ wuT2, const float* __restrict__ wuT3,
    const float* __restrict__ wuT4, const float* __restrict__ wuT5,
    const float* __restrict__ b0, const float* __restrict__ b1,
    const float* __restrict__ b2, const float* __restrict__ b3,
    const float* __restrict__ b4, const float* __restrict__ b5,
    float* __restrict__ dout, unsigned* __restrict__ f0,
    unsigned* __restrict__ f1, unsigned* __restrict__ f2,
    unsigned* __restrict__ f3, unsigned* __restrict__ f4,
    unsigned* __restrict__ f5, unsigned* __restrict__ eps) {
  __shared__ alignas(16) float wLDS[16 * 768];  // 48 KB (max KTq=192)
  __shared__ alignas(16) float sZ[4][16][64];   // 16 KB
  __shared__ alignas(16) float sH[256];         // 1 KB
  // 65KB/WG -> 2 blocks/CU; 470 blocks co-resident (sync safe).
  const int b = blockIdx.x;
  const int tid = threadIdx.x;
  // heavy layers (L0, L4) first so they land one-per-CU; aggregators last
  if (b < 128) {
    layer_body<256, 512, 128, false, false>(b, tid, xT, h0, wuT0, b0, nullptr,
                                            f0, eps + 0, nullptr, wLDS, sZ, sH);
  } else if (b < 256) {
    layer_body<256, 512, 128, false, true>(b - 128, tid, h3, h4, wuT4, b4,
                                           nullptr, f4, eps + 4, eps + 3, wLDS,
                                           sZ, sH);
  } else if (b < 320) {
    layer_body<512, 256, 64, false, true>(b - 256, tid, h0, h1, wuT1, b1,
                                          nullptr, f1, eps + 1, eps + 0, wLDS,
                                          sZ, sH);
  } else if (b < 384) {
    layer_body<64, 256, 64, false, true>(b - 320, tid, h2, h3, wuT3, b3,
                                         nullptr, f3, eps + 3, eps + 2, wLDS,
                                         sZ, sH);
  } else if (b < 448) {
    layer_body<512, 256, 64, true, true>(b - 384, tid, h4, h5, wuT5, b5, dout,
                                         f5, eps + 5, eps + 4, wLDS, sZ, sH);
  } else if (b < 464) {
    layer_body<256, 64, 16, false, true>(b - 448, tid, h1, h2, wuT2, b2,
                                         nullptr, f2, eps + 2, eps + 1, wLDS,
                                         sZ, sH);
  } else {
    const int l = b - 464;
    if (l == 0) agg_body<128>(f0, eps + 0);
    else if (l == 1) agg_body<64>(f1, eps + 1);
    else if (l == 2) agg_body<16>(f2, eps + 2);
    else if (l == 3) agg_body<64>(f3, eps + 3);
    else if (l == 4) agg_body<128>(f4, eps + 4);
    else agg_body<64>(f5, eps + 5);
  }
}

extern "C" void kernel_launch(void* const* d_in, const int* in_sizes, int n_in,
                              void* d_out, int out_size, void* d_ws,
                              size_t ws_size, hipStream_t stream) {
  (void)in_sizes; (void)n_in; (void)out_size; (void)ws_size;
  const float* x = (const float*)d_in[0];
  const float* W[6];
  const float* U[6];
  const float* B[6];
  for (int l = 0; l < 6; ++l) {
    W[l] = (const float*)d_in[1 + 3 * l];
    U[l] = (const float*)d_in[2 + 3 * l];
    B[l] = (const float*)d_in[3 + 3 * l];
  }
  char* ws = (char*)d_ws;
  // flags: [T][NWG] per layer; NWG = 128,64,16,64,128,64; then 6 epochs
  unsigned* f0 = (unsigned*)ws;
  unsigned* f1 = f0 + 128 * 256;
  unsigned* f2 = f1 + 64 * 256;
  unsigned* f3 = f2 + 16 * 256;
  unsigned* f4 = f3 + 64 * 256;
  unsigned* f5 = f4 + 128 * 256;
  unsigned* eps = f0 + 464 * 256;
  float* wuT0 = (float*)(ws + (1u << 20));
  float* wuT1 = wuT0 + (size_t)2048 * 768;
  float* wuT2 = wuT1 + (size_t)1024 * 768;
  float* wuT3 = wuT2 + (size_t)256 * 320;
  float* wuT4 = wuT3 + (size_t)1024 * 320;
  float* wuT5 = wuT4 + (size_t)2048 * 768;
  float* xT = (float*)(ws + (22u << 20));   // 16 MB
  float* h0 = (float*)(ws + (38u << 20));   // 32 MB
  float* h1 = (float*)(ws + (70u << 20));   // 16 MB
  float* h2 = (float*)(ws + (86u << 20));   // 4 MB
  float* h3 = (float*)(ws + (90u << 20));   // 16 MB
  float* h4 = (float*)(ws + (106u << 20));  // 32 MB
  float* h5 = (float*)(ws + (138u << 20));  // 16 MB (full T, no ring)

  hipMemsetAsync(f0, 0, (464 * 256 + 8) * sizeof(unsigned), stream);
  xpose_in<<<256, 256, 0, stream>>>(x, xT);
  pack_wu<<<dim3(32, 12), 256, 0, stream>>>(W[0], U[0], wuT0, 256, 512);
  pack_wu<<<dim3(16, 12), 256, 0, stream>>>(W[1], U[1], wuT1, 512, 256);
  pack_wu<<<dim3(4, 5), 256, 0, stream>>>(W[2], U[2], wuT2, 256, 64);
  pack_wu<<<dim3(16, 5), 256, 0, stream>>>(W[3], U[3], wuT3, 64, 256);
  pack_wu<<<dim3(32, 12), 256, 0, stream>>>(W[4], U[4], wuT4, 256, 512);
  pack_wu<<<dim3(16, 12), 256, 0, stream>>>(W[5], U[5], wuT5, 512, 256);

  lstm_fused<<<470, 256, 0, stream>>>(xT, h0, h1, h2, h3, h4, h5, wuT0, wuT1,
                                      wuT2, wuT3, wuT4, wuT5, B[0], B[1], B[2],
                                      B[3], B[4], B[5], (float*)d_out, f0, f1,
                                      f2, f3, f4, f5, eps);
}

// Round 10
// 3371.335 us; speedup vs baseline: 1.3067x; 1.0262x over previous
//
#include <hip/hip_runtime.h>
#include <stdint.h>

#define AGENT __HIP_MEMORY_SCOPE_AGENT
typedef unsigned long long u64;

// x[64][256][256] -> xT[t][k][b]  (k-major, batch-minor)
__global__ __launch_bounds__(256) void xpose_in(const float* __restrict__ x,
                                                float* __restrict__ xT) {
  const int t = blockIdx.x;
  const int b = threadIdx.x & 63;
  const int w = threadIdx.x >> 6;
  const float* xr = x + ((size_t)b * 256 + t) * 256;
  float* o = xT + (size_t)t * 256 * 64;
  for (int kq = w * 16; kq < w * 16 + 16; ++kq) {
    float4 v = *(const float4*)(xr + kq * 4);
    o[(size_t)(kq * 4 + 0) * 64 + b] = v.x;
    o[(size_t)(kq * 4 + 1) * 64 + b] = v.y;
    o[(size_t)(kq * 4 + 2) * 64 + b] = v.z;
    o[(size_t)(kq * 4 + 3) * 64 + b] = v.w;
  }
}

// Pack [W;U] ([KT][4H]) into quad-major per-WG blocks:
//   out[((wg*KTq + q)*16 + c)*4 + j] = WU[k=4q+j][col = g*H + wg*4 + jl],
// c = g*4 + jl. (Global layout unchanged; the bank-conflict fix is applied
// at LDS-staging time in the worker.)
__global__ __launch_bounds__(256) void pack_wu(const float* __restrict__ W,
                                               const float* __restrict__ U,
                                               float* __restrict__ out,
                                               int DIN, int H) {
  __shared__ float tile[64][65];
  const int KT = DIN + H;
  const int KTq = KT >> 2;
  const int c0 = blockIdx.x * 64;
  const int k0 = blockIdx.y * 64;
  const int tx = threadIdx.x & 63;
  const int ty = threadIdx.x >> 6;
  for (int r = ty; r < 64; r += 4) {
    const int k = k0 + r;
    tile[r][tx] = (k < DIN) ? W[(size_t)k * (4 * H) + c0 + tx]
                            : U[(size_t)(k - DIN) * (4 * H) + c0 + tx];
  }
  __syncthreads();
  for (int r = ty; r < 64; r += 4) {
    const int cg = c0 + r;
    const int g = cg / H;
    const int col = cg - g * H;
    const int wg = col >> 2;
    const int jl = col & 3;
    const int c = (g << 2) | jl;
    const int k = k0 + tx;
    const int q = k >> 2;
    const int j = k & 3;
    out[(((size_t)wg * KTq + q) * 16 + c) * 4 + j] = tile[tx][r];
  }
}

#define SB __builtin_amdgcn_sched_barrier(0)
// Round-1 lesson: macro params must NOT be named x/y/z/w (member capture).
// 8 fmas: one w-scalar WS_ times 8 batch values (two float4 halves).
#define FMA_B8(I_, WS_, XA_, XB_)                                   \
  acc[(I_) * 8 + 0] = fmaf(WS_, (XA_).x, acc[(I_) * 8 + 0]);        \
  acc[(I_) * 8 + 1] = fmaf(WS_, (XA_).y, acc[(I_) * 8 + 1]);        \
  acc[(I_) * 8 + 2] = fmaf(WS_, (XA_).z, acc[(I_) * 8 + 2]);        \
  acc[(I_) * 8 + 3] = fmaf(WS_, (XA_).w, acc[(I_) * 8 + 3]);        \
  acc[(I_) * 8 + 4] = fmaf(WS_, (XB_).x, acc[(I_) * 8 + 4]);        \
  acc[(I_) * 8 + 5] = fmaf(WS_, (XB_).y, acc[(I_) * 8 + 5]);        \
  acc[(I_) * 8 + 6] = fmaf(WS_, (XB_).z, acc[(I_) * 8 + 6]);        \
  acc[(I_) * 8 + 7] = fmaf(WS_, (XB_).w, acc[(I_) * 8 + 7]);
// One c-row over the quad's 4 k's (WV_ components = k).
#define FMA_ROW32(I_, WV_)                 \
  FMA_B8(I_, (WV_).x, x0a_, x0b_)          \
  FMA_B8(I_, (WV_).y, x1a_, x1b_)          \
  FMA_B8(I_, (WV_).z, x2a_, x2b_)          \
  FMA_B8(I_, (WV_).w, x3a_, x3b_)

// (8c,8b) register tile, 16 FMA/fill (round-9 win: fills are the binder).
// Round-10: w-LDS layout de-conflicted. Round-9's [q][c] layout put all 8
// lane-groups' (k4,cq) read bases at multiples of 128B -> SAME 4-bank quad
// -> 8-way conflict on EVERY w-read (SQ_LDS_BANK_CONFLICT 512M, ~18k
// cyc/CU/tick). New layout: quad-row stride 17 float4s (r>=8 half shifted
// +1) and slice slab = QL*17+2, making group bases k4*(SLAB%8)+cq distinct
// mod 8 for QL in {4,8} (QL=1: one 2-way pair, free per m136). Same read
// count, same arithmetic (identical absmax).
// Wave lanes = (cq = lane>>5, k4 = (lane>>3)&3, bq = lane&7); acc[i*8+j] =
// partial z(c=cq*8+i, b=bq*8+j), K-slice (wv*4+k4). Per quad: 8 x-loads
// (dwordx4) + 8 w ds_read_b128 (conflict-free broadcast) + 256 FMA.
template <int QL>
__device__ __forceinline__ void accum88(const float4* __restrict__ sp,
                                        const float4* __restrict__ wp,
                                        float acc[64]) {
#pragma unroll 1
  for (int q = 0; q < QL; ++q) {
    const float4 x0a_ = sp[0],  x0b_ = sp[1];
    const float4 x1a_ = sp[16], x1b_ = sp[17];
    const float4 x2a_ = sp[32], x2b_ = sp[33];
    const float4 x3a_ = sp[48], x3b_ = sp[49];
    const float4 w0_ = wp[0], w1_ = wp[1], w2_ = wp[2], w3_ = wp[3];
    const float4 w4_ = wp[4], w5_ = wp[5], w6_ = wp[6], w7_ = wp[7];
    FMA_ROW32(0, w0_)
    FMA_ROW32(1, w1_)
    FMA_ROW32(2, w2_)
    FMA_ROW32(3, w3_)
    FMA_ROW32(4, w4_)
    FMA_ROW32(5, w5_)
    FMA_ROW32(6, w6_)
    FMA_ROW32(7, w7_)
    SB;  // cap live regs per quad
    sp += 64;
    wp += 17;  // swizzled row stride
  }
}

// Dedicated per-layer aggregator: one wave gathers this layer's NWG per-WG
// flags for tick t, then publishes a single monotonic epoch word.
template <int NWG>
__device__ __forceinline__ void agg_body(unsigned* __restrict__ flg,
                                         unsigned* __restrict__ ep) {
  const int tid = threadIdx.x;
  if (tid >= 64) return;  // single wave
  for (int t = 0; t < 256; ++t) {
    unsigned* base = flg + (size_t)t * NWG;
    if (NWG <= 64) {
      if (tid < NWG) {
        while (__hip_atomic_load(base + tid, __ATOMIC_RELAXED, AGENT) == 0u)
          __builtin_amdgcn_s_sleep(1);
      }
    } else {
      while (__hip_atomic_load(base + tid, __ATOMIC_RELAXED, AGENT) == 0u)
        __builtin_amdgcn_s_sleep(1);
      while (__hip_atomic_load(base + 64 + tid, __ATOMIC_RELAXED, AGENT) == 0u)
        __builtin_amdgcn_s_sleep(1);
    }
    asm volatile("s_waitcnt vmcnt(0)" ::: "memory");
    if (tid == 0)
      __hip_atomic_store(ep, (unsigned)(t + 1), __ATOMIC_RELAXED, AGENT);
  }
}

// One pipelined LSTM layer. 256-thread WG owns hidden quad wg (4 units);
// weights staged ONCE into LDS in the bank-swizzled layout (<=52KB).
// 16 K-slices (4 waves x 4 intra-wave via lane k4); 2-round ds_swizzle
// butterfly (xor8=0x201F, xor16=0x401F over lane bits 3-4) merges the
// intra-wave slices; then the sZ[4] reduction / epilogue / publish /
// flag-epoch sync are unchanged from round 9.
template <int DIN, int H, int NWG, bool FIN, bool XCOH>
__device__ __forceinline__ void layer_body(
    int wg, int tid, const float* __restrict__ xin, float* __restrict__ hseq,
    const float* __restrict__ wP, const float* __restrict__ bias,
    float* __restrict__ dout, unsigned* __restrict__ selfF,
    unsigned* __restrict__ selfE, unsigned* __restrict__ prevE,
    float* __restrict__ wL, float (*sZ)[16][64], float* sH) {
  constexpr int KT = DIN + H;
  constexpr int KTq = KT / 4;
  constexpr int XQ4 = DIN / 4;     // x quads total
  constexpr int QLX = DIN / 64;    // quads per K-slice (x part)
  constexpr int QLH = H / 64;      // quads per K-slice (h part)
  constexpr int SLABX = QLX * 17 + 2;  // float4s per x slice slab
  constexpr int SLABH = QLH * 17 + 2;  // float4s per h slice slab
  constexpr int T = 256;
  static_assert(DIN % 64 == 0 && H % 64 == 0, "16-way K-slicing");

  const int lane = tid & 63;
  const int wv = tid >> 6;           // wave: K-quarter; unit jl in epilogue
  const int cq = lane >> 5;          // c-half (8 rows)
  const int k4 = (lane >> 3) & 3;    // intra-wave K-slice (lane bits 3-4)
  const int bq = lane & 7;           // batch octet
  const int slice = wv * 4 + k4;     // global K-slice 0..15

  // ---- stage weights into LDS (once), bank-swizzled layout:
  // x part: [slice][q][r] -> slice*SLABX + q*17 + r + (r>>3)
  // h part: 16*SLABX + [slice][q][r] -> ... + slice*SLABH + q*17 + r + (r>>3)
  {
    float4* wl = (float4*)wL;
    const float4* wp = (const float4*)wP + (size_t)wg * KTq * 16;
    for (int i = tid; i < KTq * 16; i += 256) {
      const int qg = i >> 4;
      const int c = i & 15;
      int lidx;
      if (qg < XQ4) {
        lidx = (qg / QLX) * SLABX + (qg % QLX) * 17 + c + (c >> 3);
      } else {
        const int qh = qg - XQ4;
        lidx = 16 * SLABX + (qh / QLH) * SLABH + (qh % QLH) * 17 + c + (c >> 3);
      }
      wl[lidx] = wp[i];
    }
  }
  // read bases: +cq*9 lands on the shifted half for cq=1 (r + (r>>3))
  const float4* wbx = (const float4*)wL + (size_t)slice * SLABX + cq * 9;
  const float4* wbh =
      (const float4*)wL + (size_t)16 * SLABX + (size_t)slice * SLABH + cq * 9;

  float bz[4];
#pragma unroll
  for (int g = 0; g < 4; ++g) bz[g] = bias[g * H + wg * 4 + wv];
  float cst = 0.f;
  __syncthreads();

  for (int t = 0; t < T; ++t) {
    float acc[64];
#pragma unroll
    for (int c = 0; c < 64; ++c) acc[c] = 0.f;

    if (!XCOH) {
      // layer 0: x static — overlap input projection with waiting for peers
      accum88<QLX>((const float4*)(xin + (size_t)t * DIN * 64) +
                       (size_t)slice * QLX * 64 + bq * 2,
                   wbx, acc);
    }
    // single-lane epoch polls: tid 0 -> own layer (t-1 done); tid 64 -> prev
    if (t > 0 && tid == 0) {
      while (__hip_atomic_load(selfE, __ATOMIC_RELAXED, AGENT) < (unsigned)t)
        __builtin_amdgcn_s_sleep(2);
    }
    if (XCOH && tid == 64) {
      while (__hip_atomic_load(prevE, __ATOMIC_RELAXED, AGENT) <
             (unsigned)(t + 1))
        __builtin_amdgcn_s_sleep(2);
    }
    __syncthreads();
    asm volatile("" ::: "memory");  // no compiler hoist of loads above polls

    if (XCOH) {
      accum88<QLX>((const float4*)(xin + (size_t)t * DIN * 64) +
                       (size_t)slice * QLX * 64 + bq * 2,
                   wbx, acc);
    }
    if (t > 0) {
      accum88<QLH>((const float4*)(hseq + (size_t)(t - 1) * H * 64) +
                       (size_t)slice * QLH * 64 + bq * 2,
                   wbh, acc);
    }

    // ---- intra-wave K-merge: butterfly over lane bits 3-4 (all lanes) ----
#pragma unroll
    for (int r = 0; r < 64; ++r) {
      const int v = __builtin_amdgcn_ds_swizzle(__float_as_int(acc[r]),
                                                0x201F);  // xor lane^8
      acc[r] += __int_as_float(v);
    }
#pragma unroll
    for (int r = 0; r < 64; ++r) {
      const int v = __builtin_amdgcn_ds_swizzle(__float_as_int(acc[r]),
                                                0x401F);  // xor lane^16
      acc[r] += __int_as_float(v);
    }

    // wave partial -> sZ[wv][c][b] (k4==0 lanes carry the merged values)
    if (k4 == 0) {
#pragma unroll
      for (int i = 0; i < 8; ++i) {
#pragma unroll
        for (int h = 0; h < 2; ++h) {
          *(float4*)&sZ[wv][cq * 8 + i][bq * 8 + h * 4] =
              make_float4(acc[i * 8 + h * 4 + 0], acc[i * 8 + h * 4 + 1],
                          acc[i * 8 + h * 4 + 2], acc[i * 8 + h * 4 + 3]);
        }
      }
    }
    __syncthreads();

    float z[4];
#pragma unroll
    for (int g = 0; g < 4; ++g) {
      z[g] = bz[g];
#pragma unroll
      for (int k = 0; k < 4; ++k) z[g] += sZ[k][g * 4 + wv][lane];
    }
    const float ig = 1.f / (1.f + __expf(-z[0]));
    const float fg = 1.f / (1.f + __expf(-z[1]));
    const float gg = FIN ? tanhf(z[2]) : fmaxf(z[2], 0.f);
    const float og = 1.f / (1.f + __expf(-z[3]));
    cst = fg * cst + ig * gg;
    const float ca = FIN ? tanhf(cst) : fmaxf(cst, 0.f);
    const float h = og * ca;
    sH[lane * 4 + wv] = h;  // [b][jl]
    if (FIN && t == T - 1) dout[(size_t)lane * H + wg * 4 + wv] = h;
    __syncthreads();

    // wave 0 publishes the WG's 4 unit-rows in [t][unit][b] layout
    // (agent write-through, coalesced 256B per row), then signals.
    if (wv == 0) {
      float* hw = hseq + (size_t)t * H * 64 + (size_t)(wg * 4) * 64 + lane;
#pragma unroll
      for (int jl = 0; jl < 4; ++jl) {
        __hip_atomic_store(hw + jl * 64, sH[lane * 4 + jl], __ATOMIC_RELAXED,
                           AGENT);
      }
      asm volatile("s_waitcnt vmcnt(0)" ::: "memory");
      if (tid == 0)
        __hip_atomic_store(&selfF[t * NWG + wg], 1u, __ATOMIC_RELAXED, AGENT);
    }
  }
}

__global__ __launch_bounds__(256, 2) void lstm_fused(
    const float* __restrict__ xT, float* __restrict__ h0,
    float* __restrict__ h1, float* __restrict__ h2, float* __restrict__ h3,
    float* __restrict__ h4, float* __restrict__ h5,
    const float* __restrict__ wuT0, const float* __restrict__ wuT1,
    const float* __restrict__ wuT2, const float* __restrict__ wuT3,
    const float* __restrict__ wuT4, const float* __restrict__ wuT5,
    const float* __restrict__ b0, const float* __restrict__ b1,
    const float* __restrict__ b2, const float* __restrict__ b3,
    const float* __restrict__ b4, const float* __restrict__ b5,
    float* __restrict__ dout, unsigned* __restrict__ f0,
    unsigned* __restrict__ f1, unsigned* __restrict__ f2,
    unsigned* __restrict__ f3, unsigned* __restrict__ f4,
    unsigned* __restrict__ f5, unsigned* __restrict__ eps) {
  // max 17*KTq + 64 = 3328 float4s (KTq=192) = 52 KB
  __shared__ alignas(16) float wLDS[4 * 3328];
  __shared__ alignas(16) float sZ[4][16][64];   // 16 KB
  __shared__ alignas(16) float sH[256];         // 1 KB
  // ~70 KB/WG -> 2 blocks/CU; 470 blocks co-resident (sync safe).
  const int b = blockIdx.x;
  const int tid = threadIdx.x;
  // heavy layers (L0, L4) first so they land one-per-CU; aggregators last
  if (b < 128) {
    layer_body<256, 512, 128, false, false>(b, tid, xT, h0, wuT0, b0, nullptr,
                                            f0, eps + 0, nullptr, wLDS, sZ, sH);
  } else if (b < 256) {
    layer_body<256, 512, 128, false, true>(b - 128, tid, h3, h4, wuT4, b4,
                                           nullptr, f4, eps + 4, eps + 3, wLDS,
                                           sZ, sH);
  } else if (b < 320) {
    layer_body<512, 256, 64, false, true>(b - 256, tid, h0, h1, wuT1, b1,
                                          nullptr, f1, eps + 1, eps + 0, wLDS,
                                          sZ, sH);
  } else if (b < 384) {
    layer_body<64, 256, 64, false, true>(b - 320, tid, h2, h3, wuT3, b3,
                                         nullptr, f3, eps + 3, eps + 2, wLDS,
                                         sZ, sH);
  } else if (b < 448) {
    layer_body<512, 256, 64, true, true>(b - 384, tid, h4, h5, wuT5, b5, dout,
                                         f5, eps + 5, eps + 4, wLDS, sZ, sH);
  } else if (b < 464) {
    layer_body<256, 64, 16, false, true>(b - 448, tid, h1, h2, wuT2, b2,
                                         nullptr, f2, eps + 2, eps + 1, wLDS,
                                         sZ, sH);
  } else {
    const int l = b - 464;
    if (l == 0) agg_body<128>(f0, eps + 0);
    else if (l == 1) agg_body<64>(f1, eps + 1);
    else if (l == 2) agg_body<16>(f2, eps + 2);
    else if (l == 3) agg_body<64>(f3, eps + 3);
    else if (l == 4) agg_body<128>(f4, eps + 4);
    else agg_body<64>(f5, eps + 5);
  }
}

extern "C" void kernel_launch(void* const* d_in, const int* in_sizes, int n_in,
                              void* d_out, int out_size, void* d_ws,
                              size_t ws_size, hipStream_t stream) {
  (void)in_sizes; (void)n_in; (void)out_size; (void)ws_size;
  const float* x = (const float*)d_in[0];
  const float* W[6];
  const float* U[6];
  const float* B[6];
  for (int l = 0; l < 6; ++l) {
    W[l] = (const float*)d_in[1 + 3 * l];
    U[l] = (const float*)d_in[2 + 3 * l];
    B[l] = (const float*)d_in[3 + 3 * l];
  }
  char* ws = (char*)d_ws;
  // flags: [T][NWG] per layer; NWG = 128,64,16,64,128,64; then 6 epochs
  unsigned* f0 = (unsigned*)ws;
  unsigned* f1 = f0 + 128 * 256;
  unsigned* f2 = f1 + 64 * 256;
  unsigned* f3 = f2 + 16 * 256;
  unsigned* f4 = f3 + 64 * 256;
  unsigned* f5 = f4 + 128 * 256;
  unsigned* eps = f0 + 464 * 256;
  float* wuT0 = (float*)(ws + (1u << 20));
  float* wuT1 = wuT0 + (size_t)2048 * 768;
  float* wuT2 = wuT1 + (size_t)1024 * 768;
  float* wuT3 = wuT2 + (size_t)256 * 320;
  float* wuT4 = wuT3 + (size_t)1024 * 320;
  float* wuT5 = wuT4 + (size_t)2048 * 768;
  float* xT = (float*)(ws + (22u << 20));   // 16 MB
  float* h0 = (float*)(ws + (38u << 20));   // 32 MB
  float* h1 = (float*)(ws + (70u << 20));   // 16 MB
  float* h2 = (float*)(ws + (86u << 20));   // 4 MB
  float* h3 = (float*)(ws + (90u << 20));   // 16 MB
  float* h4 = (float*)(ws + (106u << 20));  // 32 MB
  float* h5 = (float*)(ws + (138u << 20));  // 16 MB (full T, no ring)

  hipMemsetAsync(f0, 0, (464 * 256 + 8) * sizeof(unsigned), stream);
  xpose_in<<<256, 256, 0, stream>>>(x, xT);
  pack_wu<<<dim3(32, 12), 256, 0, stream>>>(W[0], U[0], wuT0, 256, 512);
  pack_wu<<<dim3(16, 12), 256, 0, stream>>>(W[1], U[1], wuT1, 512, 256);
  pack_wu<<<dim3(4, 5), 256, 0, stream>>>(W[2], U[2], wuT2, 256, 64);
  pack_wu<<<dim3(16, 5), 256, 0, stream>>>(W[3], U[3], wuT3, 64, 256);
  pack_wu<<<dim3(32, 12), 256, 0, stream>>>(W[4], U[4], wuT4, 256, 512);
  pack_wu<<<dim3(16, 12), 256, 0, stream>>>(W[5], U[5], wuT5, 512, 256);

  lstm_fused<<<470, 256, 0, stream>>>(xT, h0, h1, h2, h3, h4, h5, wuT0, wuT1,
                                      wuT2, wuT3, wuT4, wuT5, B[0], B[1], B[2],
                                      B[3], B[4], B[5], (float*)d_out, f0, f1,
                                      f2, f3, f4, f5, eps);
}